// Round 8
// baseline (181.898 us; speedup 1.0000x reference)
//
#include <hip/hip_runtime.h>
#include <math.h>

#define BB   4
#define DIM  64
#define RES  128
#define WIN  16
#define WS   32

// ---------------------------------------------------------------------------
// Kernel 1: pooled[b,w,c] = mean over 32x32 window of depthwise 3x3 conv.
// mean(conv) = (1/1024) * sum_taps k[tap] * S(tap), where S(tap) is the sum of
// x over the window intersected with the shifted window. S derives from
// total, first/last row sums, first/last col sums, and 4 corners.
// ---------------------------------------------------------------------------
__global__ __launch_bounds__(256) void k_pooled(
    const float* __restrict__ x, const float* __restrict__ conv1_w,
    float* __restrict__ pooled)
{
  const int blk = blockIdx.x;          // b*16 + w
  const int b = blk >> 4, w = blk & 15;
  const int wy = w >> 2, wx = w & 3;
  const int c = threadIdx.x & 63, q = threadIdx.x >> 6;   // 4 waves, 8 rows each
  const float* xb = x + (size_t)b * RES * RES * DIM + c;

  float T = 0.f, R0 = 0.f, RL = 0.f, C0 = 0.f, CL = 0.f;
  for (int ii = 0; ii < 8; ++ii) {
    const int i  = q * 8 + ii;                 // row within window
    const int gr = wy * WS + i;                // global row
    const float* xr = xb + (size_t)(gr * RES + wx * WS) * DIM;
    float rs = 0.f, v0 = 0.f, vL = 0.f;
    for (int j = 0; j < 32; ++j) {
      float v = xr[(size_t)j * DIM];
      rs += v;
      if (j == 0)  v0 = v;
      if (j == 31) vL = v;
    }
    T += rs; C0 += v0; CL += vL;
    if (i == 0)  R0 += rs;
    if (i == 31) RL += rs;
  }

  __shared__ float part[4][5][64];
  part[q][0][c] = T;  part[q][1][c] = R0; part[q][2][c] = RL;
  part[q][3][c] = C0; part[q][4][c] = CL;
  __syncthreads();

  if (q == 0) {
    float t = 0, r0 = 0, rl = 0, c0 = 0, cl = 0;
    for (int qq = 0; qq < 4; ++qq) {
      t += part[qq][0][c]; r0 += part[qq][1][c]; rl += part[qq][2][c];
      c0 += part[qq][3][c]; cl += part[qq][4][c];
    }
    const size_t b00 = (size_t)(wy * WS * RES + wx * WS) * DIM;
    const float x00 = xb[b00];
    const float x0L = xb[b00 + 31 * DIM];
    const float xL0 = xb[b00 + (size_t)31 * RES * DIM];
    const float xLL = xb[b00 + (size_t)31 * RES * DIM + 31 * DIM];

    const float* bw = conv1_w + (size_t)(w * DIM + c) * 9;
    float p = 0.f;
#pragma unroll
    for (int ky = 0; ky < 3; ++ky) {
#pragma unroll
      for (int kx = 0; kx < 3; ++kx) {
        const int dy = ky - 1, dx = kx - 1;
        float S = t;
        if (dy == 1)  S -= r0;   // shifted read excludes window row 0
        if (dy == -1) S -= rl;   // excludes last row
        if (dx == 1)  S -= c0;
        if (dx == -1) S -= cl;
        if (dy == 1 && dx == 1)   S += x00;  // corner subtracted twice
        if (dy == 1 && dx == -1)  S += x0L;
        if (dy == -1 && dx == 1)  S += xL0;
        if (dy == -1 && dx == -1) S += xLL;
        p += bw[ky * 3 + kx] * S;
      }
    }
    pooled[blk * 64 + c] = p * (1.0f / 1024.0f);
  }
}

// ---------------------------------------------------------------------------
// Kernel 2: per-(b,o) block. Recomputes the tiny MLP (cheap, avoids a launch),
// then Keff[b,o,c,tap] = gk_b*f1 + sum_g w2[g]*base[g,c,tap]*(fw[o,g,c]+gk_w[g]*f1)
// ---------------------------------------------------------------------------
__global__ __launch_bounds__(576) void k_keff(
    const float* __restrict__ pooled, const float* __restrict__ conv1_w,
    const float* __restrict__ dc_w, const float* __restrict__ dc_b,
    const float* __restrict__ l1_w, const float* __restrict__ l1_b,
    const float* __restrict__ l2_w, const float* __restrict__ l2_b,
    const float* __restrict__ gk_w, const float* __restrict__ gk_b,
    const float* __restrict__ fus_w, float* __restrict__ keff)
{
  const int b = blockIdx.x >> 6, o = blockIdx.x & 63;
  const int tid = threadIdx.x;
  __shared__ float w1s[16], hs[64], w2s[16], gkws[16];

  if (tid < 16) {
    float s = dc_b[tid];
    const float* p  = pooled + b * 1024 + tid * 64;
    const float* dw = dc_w + tid * 64;
    for (int cc = 0; cc < 64; ++cc) s += p[cc] * dw[cc];
    w1s[tid] = s;
    gkws[tid] = gk_w[tid];
  }
  __syncthreads();
  if (tid < 64) {
    float s = l1_b[tid];
    for (int g = 0; g < 16; ++g) s += w1s[g] * l1_w[tid * 16 + g];
    hs[tid] = 0.5f * s * (1.0f + erff(s * 0.70710678118654752f));  // exact GELU
  }
  __syncthreads();
  if (tid < 16) {
    float s = l2_b[tid];
    for (int j = 0; j < 64; ++j) s += hs[j] * l2_w[tid * 64 + j];
    w2s[tid] = 1.0f / (1.0f + expf(-s));
  }
  __syncthreads();

  const int c = tid / 9, t = tid % 9;   // tid < 576
  const float f1 = fus_w[o * 1088 + 1024 + c];
  float acc = gk_b[0] * f1;
#pragma unroll
  for (int g = 0; g < 16; ++g) {
    acc += w2s[g] * conv1_w[(size_t)(g * 64 + c) * 9 + t] *
           (fus_w[o * 1088 + g * 64 + c] + gkws[g] * f1);
  }
  keff[((size_t)(b * 64 + o) * 64 + c) * 9 + t] = acc;
}

// ---------------------------------------------------------------------------
// Kernel 3: dense per-batch 3x3 conv, 64->64 ch, via LDS-tiled fp32 FMA.
// Block = (b, image row). 512 threads: to=tid&15 (4 outs each), tp=tid>>4
// (4 cols each). LDS: x halo rows [3][16ch][140] + Keff chunk [16][9][64].
// c-chunks of 16, 4 iterations.
// ---------------------------------------------------------------------------
__global__ __launch_bounds__(512, 4) void k_conv(
    const float* __restrict__ x, const float* __restrict__ keff,
    const float* __restrict__ fus_b, float* __restrict__ out)
{
  const int bid = blockIdx.x;
  const int b = bid >> 7;          // 128 rows per batch
  const int row = bid & 127;
  const int tid = threadIdx.x;
  const int to = tid & 15;         // output group: o = to*4+oi
  const int tp = tid >> 4;         // pixel group: col = tp*4+pi

  __shared__ float xs[3][16][140];   // [halo row][ch][col+4], stride 140 -> b128-aligned
  __shared__ float ks[16][9][64];    // [ch][tap][o]

  float acc[4][4];                   // [pi][oi]
  {
    const float4 fb = *(const float4*)(fus_b + to * 4);
#pragma unroll
    for (int pi = 0; pi < 4; ++pi) {
      acc[pi][0] = fb.x; acc[pi][1] = fb.y; acc[pi][2] = fb.z; acc[pi][3] = fb.w;
    }
  }

  const float* xb = x + (size_t)b * RES * RES * DIM;
  const size_t kbase = (size_t)b * 64 * 576;

  for (int ci = 0; ci < 4; ++ci) {
    const int c0 = ci * 16;
    // ---- stage x halo rows (zero-padded) ----
    for (int idx = tid; idx < 3 * 130 * 16; idx += 512) {
      const int cl  = idx & 15;
      const int pos = idx >> 4;
      const int r   = pos / 130;
      const int jj  = pos % 130 - 1;       // -1..128
      const int gr  = row - 1 + r;
      float v = 0.f;
      if (gr >= 0 && gr < RES && jj >= 0 && jj < RES)
        v = xb[(size_t)(gr * RES + jj) * DIM + c0 + cl];
      xs[r][cl][4 + jj] = v;               // col j at index j+4
    }
    // ---- stage Keff chunk ----
    for (int idx = tid; idx < 16 * 9 * 64; idx += 512) {
      const int o  = idx & 63;
      const int tt = (idx >> 6) % 9;
      const int cl = idx / 576;
      ks[cl][tt][o] = keff[kbase + (size_t)o * 576 + (c0 + cl) * 9 + tt];
    }
    __syncthreads();

#pragma unroll 2
    for (int cc = 0; cc < 16; ++cc) {
#pragma unroll
      for (int r = 0; r < 3; ++r) {
        const float* xbase = &xs[r][cc][3 + tp * 4];
        const float  xl = xbase[0];
        const float4 xm = *(const float4*)(xbase + 1);   // 16B-aligned
        const float  xr = xbase[5];
        const float xv[6] = {xl, xm.x, xm.y, xm.z, xm.w, xr};
#pragma unroll
        for (int kx = 0; kx < 3; ++kx) {
          const float4 kk = *(const float4*)&ks[cc][r * 3 + kx][to * 4];
#pragma unroll
          for (int pi = 0; pi < 4; ++pi) {
            const float xf = xv[pi + kx];
            acc[pi][0] = fmaf(kk.x, xf, acc[pi][0]);
            acc[pi][1] = fmaf(kk.y, xf, acc[pi][1]);
            acc[pi][2] = fmaf(kk.z, xf, acc[pi][2]);
            acc[pi][3] = fmaf(kk.w, xf, acc[pi][3]);
          }
        }
      }
    }
    __syncthreads();
  }

  // ---- store: out[b, row*128+col, o], float4 over oi ----
  float* ob = out + ((size_t)(b * RES * RES + row * RES + tp * 4)) * DIM + to * 4;
#pragma unroll
  for (int pi = 0; pi < 4; ++pi) {
    *(float4*)(ob + (size_t)pi * DIM) =
        make_float4(acc[pi][0], acc[pi][1], acc[pi][2], acc[pi][3]);
  }
}

// ---------------------------------------------------------------------------
extern "C" void kernel_launch(void* const* d_in, const int* in_sizes, int n_in,
                              void* d_out, int out_size, void* d_ws, size_t ws_size,
                              hipStream_t stream) {
  const float* x       = (const float*)d_in[0];
  const float* conv1_w = (const float*)d_in[1];
  const float* dc_w    = (const float*)d_in[2];
  const float* dc_b    = (const float*)d_in[3];
  const float* l1_w    = (const float*)d_in[4];
  const float* l1_b    = (const float*)d_in[5];
  const float* l2_w    = (const float*)d_in[6];
  const float* l2_b    = (const float*)d_in[7];
  const float* gk_w    = (const float*)d_in[8];
  const float* gk_b    = (const float*)d_in[9];
  const float* fus_w   = (const float*)d_in[10];
  const float* fus_b   = (const float*)d_in[11];
  float* out = (float*)d_out;

  // workspace: pooled (4096 f) + keff (147456 f) = ~606 KB
  float* pooled = (float*)d_ws;
  float* keff   = pooled + BB * WIN * DIM;

  hipLaunchKernelGGL(k_pooled, dim3(BB * WIN), dim3(256), 0, stream,
                     x, conv1_w, pooled);
  hipLaunchKernelGGL(k_keff, dim3(BB * 64), dim3(576), 0, stream,
                     pooled, conv1_w, dc_w, dc_b, l1_w, l1_b, l2_w, l2_b,
                     gk_w, gk_b, fus_w, keff);
  hipLaunchKernelGGL(k_conv, dim3(BB * RES), dim3(512), 0, stream,
                     x, keff, fus_b, out);
}

// Round 11
// 143.745 us; speedup vs baseline: 1.2654x; 1.2654x over previous
//
#include <hip/hip_runtime.h>
#include <math.h>

#define BB   4
#define DIM  64
#define RES  128
#define WIN  16
#define WS   32

typedef __attribute__((ext_vector_type(8))) short bf16x8;
typedef __attribute__((ext_vector_type(4))) float f32x4;

static __device__ __forceinline__ unsigned short bf16_rne(float f) {
  unsigned int u = __float_as_uint(f);
  u += 0x7FFFu + ((u >> 16) & 1u);
  return (unsigned short)(u >> 16);
}
static __device__ __forceinline__ float bf16_f(unsigned short h) {
  return __uint_as_float(((unsigned int)h) << 16);
}

// ---------------------------------------------------------------------------
// Kernel 1: pooled[b,w,c] = mean over 32x32 window of depthwise 3x3 conv.
// Shifted-window-sum algebra (total/edges/corners). 1024 threads: 16 row-
// groups x 64 channels.
// ---------------------------------------------------------------------------
__global__ __launch_bounds__(1024) void k_pooled(
    const float* __restrict__ x, const float* __restrict__ conv1_w,
    float* __restrict__ pooled)
{
  const int blk = blockIdx.x;          // b*16 + w
  const int b = blk >> 4, w = blk & 15;
  const int wy = w >> 2, wx = w & 3;
  const int c = threadIdx.x & 63, rg = threadIdx.x >> 6;   // 16 row-groups
  const float* xb = x + (size_t)b * RES * RES * DIM + c;

  float T = 0.f, R0 = 0.f, RL = 0.f, C0 = 0.f, CL = 0.f;
  for (int ii = 0; ii < 2; ++ii) {
    const int i  = rg * 2 + ii;                // row within window
    const int gr = wy * WS + i;                // global row
    const float* xr = xb + (size_t)(gr * RES + wx * WS) * DIM;
    float rs = 0.f, v0 = 0.f, vL = 0.f;
#pragma unroll 8
    for (int j = 0; j < 32; ++j) {
      float v = xr[(size_t)j * DIM];
      rs += v;
      if (j == 0)  v0 = v;
      if (j == 31) vL = v;
    }
    T += rs; C0 += v0; CL += vL;
    if (i == 0)  R0 += rs;
    if (i == 31) RL += rs;
  }

  __shared__ float part[16][5][64];
  part[rg][0][c] = T;  part[rg][1][c] = R0; part[rg][2][c] = RL;
  part[rg][3][c] = C0; part[rg][4][c] = CL;
  __syncthreads();

  if (threadIdx.x < 64) {
    const int cc = threadIdx.x;
    float t = 0, r0 = 0, rl = 0, c0 = 0, cl = 0;
#pragma unroll
    for (int q = 0; q < 16; ++q) {
      t += part[q][0][cc]; r0 += part[q][1][cc]; rl += part[q][2][cc];
      c0 += part[q][3][cc]; cl += part[q][4][cc];
    }
    const float* xc = x + (size_t)b * RES * RES * DIM + cc;
    const size_t b00 = (size_t)(wy * WS * RES + wx * WS) * DIM;
    const float x00 = xc[b00];
    const float x0L = xc[b00 + 31 * DIM];
    const float xL0 = xc[b00 + (size_t)31 * RES * DIM];
    const float xLL = xc[b00 + (size_t)31 * RES * DIM + 31 * DIM];

    const float* bw = conv1_w + (size_t)(w * DIM + cc) * 9;
    float p = 0.f;
#pragma unroll
    for (int ky = 0; ky < 3; ++ky) {
#pragma unroll
      for (int kx = 0; kx < 3; ++kx) {
        const int dy = ky - 1, dx = kx - 1;
        float S = t;
        if (dy == 1)  S -= r0;
        if (dy == -1) S -= rl;
        if (dx == 1)  S -= c0;
        if (dx == -1) S -= cl;
        if (dy == 1 && dx == 1)   S += x00;
        if (dy == 1 && dx == -1)  S += x0L;
        if (dy == -1 && dx == 1)  S += xL0;
        if (dy == -1 && dx == -1) S += xLL;
        p += bw[ky * 3 + kx] * S;
      }
    }
    pooled[blk * 64 + cc] = p * (1.0f / 1024.0f);
  }
}

// ---------------------------------------------------------------------------
// Kernel 2: per-(b,o) block. Tiny MLP (recomputed per block, cheap), then
// Keff[k=tap*64+c] = gk_b*f1 + sum_g w2[g]*base[g,c,tap]*(fw[o,g,c]+gk_w[g]*f1)
// emitted TRANSPOSED and split into bf16 hi/lo: keffT_{hi,lo}[b][o][576].
// ---------------------------------------------------------------------------
__global__ __launch_bounds__(576) void k_keff(
    const float* __restrict__ pooled, const float* __restrict__ conv1_w,
    const float* __restrict__ dc_w, const float* __restrict__ dc_b,
    const float* __restrict__ l1_w, const float* __restrict__ l1_b,
    const float* __restrict__ l2_w, const float* __restrict__ l2_b,
    const float* __restrict__ gk_w, const float* __restrict__ gk_b,
    const float* __restrict__ fus_w,
    unsigned short* __restrict__ kT_hi, unsigned short* __restrict__ kT_lo)
{
  const int b = blockIdx.x >> 6, o = blockIdx.x & 63;
  const int tid = threadIdx.x;
  __shared__ float w1s[16], hs[64], w2s[16], gkws[16];

  if (tid < 16) {
    float s = dc_b[tid];
    const float* p  = pooled + b * 1024 + tid * 64;
    const float* dw = dc_w + tid * 64;
    for (int cc = 0; cc < 64; ++cc) s += p[cc] * dw[cc];
    w1s[tid] = s;
    gkws[tid] = gk_w[tid];
  }
  __syncthreads();
  if (tid < 64) {
    float s = l1_b[tid];
    for (int g = 0; g < 16; ++g) s += w1s[g] * l1_w[tid * 16 + g];
    hs[tid] = 0.5f * s * (1.0f + erff(s * 0.70710678118654752f));  // exact GELU
  }
  __syncthreads();
  if (tid < 16) {
    float s = l2_b[tid];
    for (int j = 0; j < 64; ++j) s += hs[j] * l2_w[tid * 64 + j];
    w2s[tid] = 1.0f / (1.0f + expf(-s));
  }
  __syncthreads();

  // tid IS the GEMM k-index: k = tap*64 + c
  const int tap = tid >> 6, c = tid & 63;
  const float f1 = fus_w[o * 1088 + 1024 + c];
  float acc = gk_b[0] * f1;
#pragma unroll
  for (int g = 0; g < 16; ++g) {
    acc += w2s[g] * conv1_w[(size_t)(g * 64 + c) * 9 + tap] *
           (fus_w[o * 1088 + g * 64 + c] + gkws[g] * f1);
  }
  const unsigned short h = bf16_rne(acc);
  const unsigned short lo = bf16_rne(acc - bf16_f(h));
  const size_t kidx = (size_t)(b * 64 + o) * 576 + tid;
  kT_hi[kidx] = h;
  kT_lo[kidx] = lo;
}

// ---------------------------------------------------------------------------
// Kernel 3: implicit-GEMM conv via MFMA 16x16x32 bf16, split hi/lo (3 MFMA
// per fragment-pair: hh + hl + lh; err ~2^-16 rel). Block = (b,row), 256 thr
// = 4 waves, each wave 32 px x 64 o (M_rep=2, N_rep=4). X halo rows staged
// in LDS as bf16 hi/lo (c-chunks of 32); B frags read straight from L2
// (keffT layout: k = tap*64+c contiguous => 16B lane loads). Per K-step:
// exactly one tap (uniform dy/dx).
// ---------------------------------------------------------------------------
__global__ __launch_bounds__(256, 2) void k_conv(
    const float* __restrict__ x,
    const unsigned short* __restrict__ kT_hi,
    const unsigned short* __restrict__ kT_lo,
    const float* __restrict__ fus_b, float* __restrict__ out)
{
  const int bid = blockIdx.x;
  const int b = bid >> 7, row = bid & 127;
  const int tid = threadIdx.x;
  const int l = tid & 63, wv = tid >> 6;     // lane, wave (0..3)
  const int l16 = l & 15, lq = l >> 4;       // fragment row / k-quarter

  __shared__ unsigned short xs_hi[3][130][40];  // [halo row][col+1][c-local pad40]
  __shared__ unsigned short xs_lo[3][130][40];

  f32x4 acc[2][4];
#pragma unroll
  for (int mf = 0; mf < 2; ++mf)
#pragma unroll
    for (int nf = 0; nf < 4; ++nf) acc[mf][nf] = (f32x4){0.f, 0.f, 0.f, 0.f};

  const float* xb = x + (size_t)b * RES * RES * DIM;
  const unsigned short* khB = kT_hi + (size_t)b * 64 * 576;
  const unsigned short* klB = kT_lo + (size_t)b * 64 * 576;

  for (int ch = 0; ch < 2; ++ch) {
    const int c0 = ch * 32;
    // ---- stage x halo rows (3 rows, cols -1..128 zero-padded, 32 ch) ----
    for (int i = tid; i < 3 * 130 * 8; i += 256) {
      const int rr  = i / (130 * 8);
      const int rem = i - rr * (130 * 8);
      const int cs  = rem >> 3;          // 0..129 (col+1)
      const int c4  = rem & 7;           // float4 group within 32 ch
      const int col = cs - 1;
      const int grow = row - 1 + rr;
      float4 v = make_float4(0.f, 0.f, 0.f, 0.f);
      if (grow >= 0 && grow < RES && col >= 0 && col < RES)
        v = *(const float4*)(xb + (size_t)(grow * RES + col) * DIM + c0 + c4 * 4);
      const unsigned short h0 = bf16_rne(v.x), h1 = bf16_rne(v.y),
                           h2 = bf16_rne(v.z), h3 = bf16_rne(v.w);
      const unsigned short q0 = bf16_rne(v.x - bf16_f(h0)),
                           q1 = bf16_rne(v.y - bf16_f(h1)),
                           q2 = bf16_rne(v.z - bf16_f(h2)),
                           q3 = bf16_rne(v.w - bf16_f(h3));
      *(ushort4*)&xs_hi[rr][cs][c4 * 4] = make_ushort4(h0, h1, h2, h3);
      *(ushort4*)&xs_lo[rr][cs][c4 * 4] = make_ushort4(q0, q1, q2, q3);
    }
    __syncthreads();

    const int pcol = wv * 32 + l16;
#pragma unroll
    for (int tap = 0; tap < 9; ++tap) {
      const int dy = tap / 3 - 1, dx = tap % 3 - 1;
      const int kb = tap * 64 + c0 + lq * 8;
      bf16x8 Bh[4], Bl[4];
#pragma unroll
      for (int nf = 0; nf < 4; ++nf) {
        const size_t ko = (size_t)(nf * 16 + l16) * 576 + kb;
        Bh[nf] = *(const bf16x8*)(khB + ko);
        Bl[nf] = *(const bf16x8*)(klB + ko);
      }
      bf16x8 Ah[2], Al[2];
#pragma unroll
      for (int mf = 0; mf < 2; ++mf) {
        const int cs = 1 + pcol + mf * 16 + dx;
        Ah[mf] = *(const bf16x8*)&xs_hi[dy + 1][cs][lq * 8];
        Al[mf] = *(const bf16x8*)&xs_lo[dy + 1][cs][lq * 8];
      }
#pragma unroll
      for (int mf = 0; mf < 2; ++mf)
#pragma unroll
        for (int nf = 0; nf < 4; ++nf) {
          acc[mf][nf] = __builtin_amdgcn_mfma_f32_16x16x32_bf16(
              Ah[mf], Bh[nf], acc[mf][nf], 0, 0, 0);
          acc[mf][nf] = __builtin_amdgcn_mfma_f32_16x16x32_bf16(
              Ah[mf], Bl[nf], acc[mf][nf], 0, 0, 0);
          acc[mf][nf] = __builtin_amdgcn_mfma_f32_16x16x32_bf16(
              Al[mf], Bh[nf], acc[mf][nf], 0, 0, 0);
        }
    }
    __syncthreads();
  }

  // ---- store: D frag layout col(o)=lane&15, row(px)=(lane>>4)*4+reg ----
  float fb[4];
#pragma unroll
  for (int nf = 0; nf < 4; ++nf) fb[nf] = fus_b[nf * 16 + l16];
  const size_t pbase = (size_t)b * RES * RES + (size_t)row * RES;
#pragma unroll
  for (int mf = 0; mf < 2; ++mf) {
    const int pc = wv * 32 + mf * 16 + lq * 4;
#pragma unroll
    for (int r4 = 0; r4 < 4; ++r4) {
      const size_t po = (pbase + pc + r4) * DIM;
#pragma unroll
      for (int nf = 0; nf < 4; ++nf)
        out[po + nf * 16 + l16] = acc[mf][nf][r4] + fb[nf];
    }
  }
}

// ---------------------------------------------------------------------------
extern "C" void kernel_launch(void* const* d_in, const int* in_sizes, int n_in,
                              void* d_out, int out_size, void* d_ws, size_t ws_size,
                              hipStream_t stream) {
  const float* x       = (const float*)d_in[0];
  const float* conv1_w = (const float*)d_in[1];
  const float* dc_w    = (const float*)d_in[2];
  const float* dc_b    = (const float*)d_in[3];
  const float* l1_w    = (const float*)d_in[4];
  const float* l1_b    = (const float*)d_in[5];
  const float* l2_w    = (const float*)d_in[6];
  const float* l2_b    = (const float*)d_in[7];
  const float* gk_w    = (const float*)d_in[8];
  const float* gk_b    = (const float*)d_in[9];
  const float* fus_w   = (const float*)d_in[10];
  const float* fus_b   = (const float*)d_in[11];
  float* out = (float*)d_out;

  // workspace: pooled (16 KB) | keffT_hi (288 KB) | keffT_lo (288 KB)
  float* pooled = (float*)d_ws;
  unsigned short* kT_hi = (unsigned short*)((char*)d_ws + 16384);
  unsigned short* kT_lo = kT_hi + (size_t)BB * 64 * 576;

  hipLaunchKernelGGL(k_pooled, dim3(BB * WIN), dim3(1024), 0, stream,
                     x, conv1_w, pooled);
  hipLaunchKernelGGL(k_keff, dim3(BB * 64), dim3(576), 0, stream,
                     pooled, conv1_w, dc_w, dc_b, l1_w, l1_b, l2_w, l2_b,
                     gk_w, gk_b, fus_w, kT_hi, kT_lo);
  hipLaunchKernelGGL(k_conv, dim3(BB * RES), dim3(256), 0, stream,
                     x, kT_hi, kT_lo, fus_b, out);
}

// Round 12
// 123.220 us; speedup vs baseline: 1.4762x; 1.1666x over previous
//
#include <hip/hip_runtime.h>
#include <math.h>

#define BB   4
#define DIM  64
#define RES  128
#define WIN  16
#define WS   32

typedef __attribute__((ext_vector_type(8))) short bf16x8;
typedef __attribute__((ext_vector_type(4))) float f32x4;

static __device__ __forceinline__ unsigned short bf16_rne(float f) {
  unsigned int u = __float_as_uint(f);
  u += 0x7FFFu + ((u >> 16) & 1u);
  return (unsigned short)(u >> 16);
}
static __device__ __forceinline__ float bf16_f(unsigned short h) {
  return __uint_as_float(((unsigned int)h) << 16);
}

// ---------------------------------------------------------------------------
// Kernel 1: pooled[b,w,c] = mean over 32x32 window of depthwise 3x3 conv.
// Shifted-window-sum algebra (total/edges/corners). Unchanged from r11.
// ---------------------------------------------------------------------------
__global__ __launch_bounds__(1024) void k_pooled(
    const float* __restrict__ x, const float* __restrict__ conv1_w,
    float* __restrict__ pooled)
{
  const int blk = blockIdx.x;          // b*16 + w
  const int b = blk >> 4, w = blk & 15;
  const int wy = w >> 2, wx = w & 3;
  const int c = threadIdx.x & 63, rg = threadIdx.x >> 6;   // 16 row-groups
  const float* xb = x + (size_t)b * RES * RES * DIM + c;

  float T = 0.f, R0 = 0.f, RL = 0.f, C0 = 0.f, CL = 0.f;
  for (int ii = 0; ii < 2; ++ii) {
    const int i  = rg * 2 + ii;                // row within window
    const int gr = wy * WS + i;                // global row
    const float* xr = xb + (size_t)(gr * RES + wx * WS) * DIM;
    float rs = 0.f, v0 = 0.f, vL = 0.f;
#pragma unroll 8
    for (int j = 0; j < 32; ++j) {
      float v = xr[(size_t)j * DIM];
      rs += v;
      if (j == 0)  v0 = v;
      if (j == 31) vL = v;
    }
    T += rs; C0 += v0; CL += vL;
    if (i == 0)  R0 += rs;
    if (i == 31) RL += rs;
  }

  __shared__ float part[16][5][64];
  part[rg][0][c] = T;  part[rg][1][c] = R0; part[rg][2][c] = RL;
  part[rg][3][c] = C0; part[rg][4][c] = CL;
  __syncthreads();

  if (threadIdx.x < 64) {
    const int cc = threadIdx.x;
    float t = 0, r0 = 0, rl = 0, c0 = 0, cl = 0;
#pragma unroll
    for (int q = 0; q < 16; ++q) {
      t += part[q][0][cc]; r0 += part[q][1][cc]; rl += part[q][2][cc];
      c0 += part[q][3][cc]; cl += part[q][4][cc];
    }
    const float* xc = x + (size_t)b * RES * RES * DIM + cc;
    const size_t b00 = (size_t)(wy * WS * RES + wx * WS) * DIM;
    const float x00 = xc[b00];
    const float x0L = xc[b00 + 31 * DIM];
    const float xL0 = xc[b00 + (size_t)31 * RES * DIM];
    const float xLL = xc[b00 + (size_t)31 * RES * DIM + 31 * DIM];

    const float* bw = conv1_w + (size_t)(w * DIM + cc) * 9;
    float p = 0.f;
#pragma unroll
    for (int ky = 0; ky < 3; ++ky) {
#pragma unroll
      for (int kx = 0; kx < 3; ++kx) {
        const int dy = ky - 1, dx = kx - 1;
        float S = t;
        if (dy == 1)  S -= r0;
        if (dy == -1) S -= rl;
        if (dx == 1)  S -= c0;
        if (dx == -1) S -= cl;
        if (dy == 1 && dx == 1)   S += x00;
        if (dy == 1 && dx == -1)  S += x0L;
        if (dy == -1 && dx == 1)  S += xL0;
        if (dy == -1 && dx == -1) S += xLL;
        p += bw[ky * 3 + kx] * S;
      }
    }
    pooled[blk * 64 + cc] = p * (1.0f / 1024.0f);
  }
}

// ---------------------------------------------------------------------------
// Kernel 2: tiny MLP + Keff, transposed & split bf16 hi/lo. Unchanged.
// ---------------------------------------------------------------------------
__global__ __launch_bounds__(576) void k_keff(
    const float* __restrict__ pooled, const float* __restrict__ conv1_w,
    const float* __restrict__ dc_w, const float* __restrict__ dc_b,
    const float* __restrict__ l1_w, const float* __restrict__ l1_b,
    const float* __restrict__ l2_w, const float* __restrict__ l2_b,
    const float* __restrict__ gk_w, const float* __restrict__ gk_b,
    const float* __restrict__ fus_w,
    unsigned short* __restrict__ kT_hi, unsigned short* __restrict__ kT_lo)
{
  const int b = blockIdx.x >> 6, o = blockIdx.x & 63;
  const int tid = threadIdx.x;
  __shared__ float w1s[16], hs[64], w2s[16], gkws[16];

  if (tid < 16) {
    float s = dc_b[tid];
    const float* p  = pooled + b * 1024 + tid * 64;
    const float* dw = dc_w + tid * 64;
    for (int cc = 0; cc < 64; ++cc) s += p[cc] * dw[cc];
    w1s[tid] = s;
    gkws[tid] = gk_w[tid];
  }
  __syncthreads();
  if (tid < 64) {
    float s = l1_b[tid];
    for (int g = 0; g < 16; ++g) s += w1s[g] * l1_w[tid * 16 + g];
    hs[tid] = 0.5f * s * (1.0f + erff(s * 0.70710678118654752f));  // exact GELU
  }
  __syncthreads();
  if (tid < 16) {
    float s = l2_b[tid];
    for (int j = 0; j < 64; ++j) s += hs[j] * l2_w[tid * 64 + j];
    w2s[tid] = 1.0f / (1.0f + expf(-s));
  }
  __syncthreads();

  // tid IS the GEMM k-index: k = tap*64 + c
  const int tap = tid >> 6, c = tid & 63;
  const float f1 = fus_w[o * 1088 + 1024 + c];
  float acc = gk_b[0] * f1;
#pragma unroll
  for (int g = 0; g < 16; ++g) {
    acc += w2s[g] * conv1_w[(size_t)(g * 64 + c) * 9 + tap] *
           (fus_w[o * 1088 + g * 64 + c] + gkws[g] * f1);
  }
  const unsigned short h = bf16_rne(acc);
  const unsigned short lo = bf16_rne(acc - bf16_f(h));
  const size_t kidx = (size_t)(b * 64 + o) * 576 + tid;
  kT_hi[kidx] = h;
  kT_lo[kidx] = lo;
}

// ---------------------------------------------------------------------------
// Kernel 3: implicit-GEMM conv, MFMA 16x16x32 bf16 split hi/lo.
// RESTRUCTURED vs r11: block = (b, row, half) -> 64 px x 64 o, 4 waves
// SPLIT ON o (wave owns o-slice wv*16..+16, M_rep=4, N_rep=1):
//   - zero B redundancy across waves (was 4x), B = 2 loads/lane/tap
//   - LDS 32.6 KB -> 4 blocks/CU co-resident (grid 1024), 16 waves/CU
//   - launch_bounds(256,4) caps VGPR at 128 for 4 waves/SIMD
// Same MFMA count & order -> bitwise-identical output to r11.
// ---------------------------------------------------------------------------
__global__ __launch_bounds__(256, 4) void k_conv(
    const float* __restrict__ x,
    const unsigned short* __restrict__ kT_hi,
    const unsigned short* __restrict__ kT_lo,
    const float* __restrict__ fus_b, float* __restrict__ out)
{
  const int bid = blockIdx.x;
  const int b = bid >> 8;
  const int rem = bid & 255;
  const int row = rem >> 1;
  const int colbase = (rem & 1) * 64;
  const int tid = threadIdx.x;
  const int l = tid & 63, wv = tid >> 6;     // lane, wave (o-slice)
  const int l16 = l & 15, lq = l >> 4;

  __shared__ unsigned short xs_hi[3][68][40];  // [halo row][col+1 (0..65)][32ch pad40]
  __shared__ unsigned short xs_lo[3][68][40];

  f32x4 acc[4];
#pragma unroll
  for (int mf = 0; mf < 4; ++mf) acc[mf] = (f32x4){0.f, 0.f, 0.f, 0.f};

  const float* xb = x + (size_t)b * RES * RES * DIM;
  const unsigned short* khB = kT_hi + (size_t)b * 64 * 576;
  const unsigned short* klB = kT_lo + (size_t)b * 64 * 576;

  for (int ch = 0; ch < 2; ++ch) {
    const int c0 = ch * 32;
    // ---- stage x halo rows: 3 rows x cols (colbase-1 .. colbase+64) x 32 ch ----
    for (int i = tid; i < 3 * 66 * 8; i += 256) {
      const int rr  = i / (66 * 8);
      const int rem2 = i - rr * (66 * 8);
      const int cs  = rem2 >> 3;          // 0..65
      const int c4  = rem2 & 7;           // float4 group within 32 ch
      const int col = colbase + cs - 1;
      const int grow = row - 1 + rr;
      float4 v = make_float4(0.f, 0.f, 0.f, 0.f);
      if (grow >= 0 && grow < RES && col >= 0 && col < RES)
        v = *(const float4*)(xb + (size_t)(grow * RES + col) * DIM + c0 + c4 * 4);
      const unsigned short h0 = bf16_rne(v.x), h1 = bf16_rne(v.y),
                           h2 = bf16_rne(v.z), h3 = bf16_rne(v.w);
      const unsigned short q0 = bf16_rne(v.x - bf16_f(h0)),
                           q1 = bf16_rne(v.y - bf16_f(h1)),
                           q2 = bf16_rne(v.z - bf16_f(h2)),
                           q3 = bf16_rne(v.w - bf16_f(h3));
      *(ushort4*)&xs_hi[rr][cs][c4 * 4] = make_ushort4(h0, h1, h2, h3);
      *(ushort4*)&xs_lo[rr][cs][c4 * 4] = make_ushort4(q0, q1, q2, q3);
    }
    __syncthreads();

#pragma unroll
    for (int tap = 0; tap < 9; ++tap) {
      const int dy = tap / 3 - 1, dx = tap % 3 - 1;
      const int kb = tap * 64 + c0 + lq * 8;
      // B: this wave's o-slice only (o = wv*16 + l16) — no cross-wave redundancy
      const size_t ko = (size_t)(wv * 16 + l16) * 576 + kb;
      const bf16x8 Bh = *(const bf16x8*)(khB + ko);
      const bf16x8 Bl = *(const bf16x8*)(klB + ko);
#pragma unroll
      for (int mf = 0; mf < 4; ++mf) {
        const int cs = 1 + mf * 16 + l16 + dx;   // pixel col in LDS
        const bf16x8 Ah = *(const bf16x8*)&xs_hi[dy + 1][cs][lq * 8];
        const bf16x8 Al = *(const bf16x8*)&xs_lo[dy + 1][cs][lq * 8];
        acc[mf] = __builtin_amdgcn_mfma_f32_16x16x32_bf16(Ah, Bh, acc[mf], 0, 0, 0);
        acc[mf] = __builtin_amdgcn_mfma_f32_16x16x32_bf16(Ah, Bl, acc[mf], 0, 0, 0);
        acc[mf] = __builtin_amdgcn_mfma_f32_16x16x32_bf16(Al, Bh, acc[mf], 0, 0, 0);
      }
    }
    __syncthreads();
  }

  // ---- store: D layout col(o)=lane&15, row(px)=(lane>>4)*4+reg [m89] ----
  const float fb = fus_b[wv * 16 + l16];
  const size_t pbase = (size_t)b * RES * RES + (size_t)row * RES + colbase;
#pragma unroll
  for (int mf = 0; mf < 4; ++mf) {
    const int pc = mf * 16 + lq * 4;
#pragma unroll
    for (int r4 = 0; r4 < 4; ++r4) {
      out[(pbase + pc + r4) * DIM + wv * 16 + l16] = acc[mf][r4] + fb;
    }
  }
}

// ---------------------------------------------------------------------------
extern "C" void kernel_launch(void* const* d_in, const int* in_sizes, int n_in,
                              void* d_out, int out_size, void* d_ws, size_t ws_size,
                              hipStream_t stream) {
  const float* x       = (const float*)d_in[0];
  const float* conv1_w = (const float*)d_in[1];
  const float* dc_w    = (const float*)d_in[2];
  const float* dc_b    = (const float*)d_in[3];
  const float* l1_w    = (const float*)d_in[4];
  const float* l1_b    = (const float*)d_in[5];
  const float* l2_w    = (const float*)d_in[6];
  const float* l2_b    = (const float*)d_in[7];
  const float* gk_w    = (const float*)d_in[8];
  const float* gk_b    = (const float*)d_in[9];
  const float* fus_w   = (const float*)d_in[10];
  const float* fus_b   = (const float*)d_in[11];
  float* out = (float*)d_out;

  // workspace: pooled (16 KB) | keffT_hi (288 KB) | keffT_lo (288 KB)
  float* pooled = (float*)d_ws;
  unsigned short* kT_hi = (unsigned short*)((char*)d_ws + 16384);
  unsigned short* kT_lo = kT_hi + (size_t)BB * 64 * 576;

  hipLaunchKernelGGL(k_pooled, dim3(BB * WIN), dim3(1024), 0, stream,
                     x, conv1_w, pooled);
  hipLaunchKernelGGL(k_keff, dim3(BB * 64), dim3(576), 0, stream,
                     pooled, conv1_w, dc_w, dc_b, l1_w, l1_b, l2_w, l2_b,
                     gk_w, gk_b, fus_w, kT_hi, kT_lo);
  hipLaunchKernelGGL(k_conv, dim3(BB * RES * 2), dim3(256), 0, stream,
                     x, kT_hi, kT_lo, fus_b, out);
}